// Round 2
// baseline (425.116 us; speedup 1.0000x reference)
//
#include <hip/hip_runtime.h>
#include <hip/hip_bf16.h>

// Problem constants
#define B_   64
#define L_   1024
#define H_   512
#define T_   100
#define C_   97
#define TP_  112   // T padded to 7*16

typedef __attribute__((ext_vector_type(8))) short bh8;    // 8 bf16 (4 VGPRs)
typedef __attribute__((ext_vector_type(4))) float f32x4;  // MFMA C/D

static __device__ __forceinline__ float bf2f(short v) {
  union { unsigned int u; float f; } c;
  c.u = ((unsigned int)(unsigned short)v) << 16;
  return c.f;
}
static __device__ __forceinline__ short f2bf(float f) {
  union { float f; unsigned int u; } c; c.f = f;
  unsigned int u = c.u + 0x7fffu + ((c.u >> 16) & 1u);  // RNE
  return (short)(u >> 16);
}

// ---------------------------------------------------------------------------
// k0: prep. Split pos_emb (fp32) into bf16 hi/lo, padded to 112 rows (zeros).
//     Round W_gen to bf16. Grid: 112 + 97 blocks.
// ---------------------------------------------------------------------------
__global__ __launch_bounds__(256) void k0_prep(
    const float* __restrict__ emb, const float* __restrict__ W,
    short* __restrict__ emb_hi, short* __restrict__ emb_lo,
    short* __restrict__ W_hi) {
  const int row = blockIdx.x, tid = threadIdx.x;
  if (row < TP_) {
    for (int j = tid; j < H_; j += 256) {
      float v = (row < T_) ? emb[(size_t)row * H_ + j] : 0.f;
      short h = f2bf(v);
      emb_hi[(size_t)row * H_ + j] = h;
      emb_lo[(size_t)row * H_ + j] = f2bf(v - bf2f(h));
    }
  } else {
    const int c = row - TP_;  // 0..96
    for (int j = tid; j < H_; j += 256)
      W_hi[(size_t)c * H_ + j] = f2bf(W[(size_t)c * H_ + j]);
  }
}

// ---------------------------------------------------------------------------
// K1: scores[b*L + l][t] = sum_h fmap[b,l,h] * emb[t,h]   (fp32 out)
//     fmap fp32 split in-register to bf16 hi/lo; 3 MFMAs per tile:
//     hi*hi + lo*hi + hi*lo  (error ~2^-17 relative on scores).
//     + per-block (64 l rows) partial softmax stats (max, sum-exp) per t.
// Grid 1024 (= B*L/64), block 256 (4 waves x 16 rows).
// ---------------------------------------------------------------------------
__global__ __launch_bounds__(256) void k1_scores(
    const float* __restrict__ fmap,
    const short* __restrict__ emb_hi, const short* __restrict__ emb_lo,
    float* __restrict__ scores, float* __restrict__ part) {
  __shared__ float red_m[4 * TP_];
  __shared__ float red_s[4 * TP_];
  const int tid  = threadIdx.x;
  const int wave = tid >> 6, lane = tid & 63;
  const int quad = lane >> 4, cc = lane & 15;
  const int m0 = blockIdx.x * 64 + wave * 16;   // global row base for this wave

  f32x4 acc[7];
#pragma unroll
  for (int i = 0; i < 7; ++i) acc[i] = (f32x4){0.f, 0.f, 0.f, 0.f};

  const float* aptr = fmap + (size_t)(m0 + cc) * H_ + quad * 8;
  for (int k = 0; k < H_; k += 32) {
    float4 a0 = *(const float4*)(aptr + k);
    float4 a1 = *(const float4*)(aptr + k + 4);
    float av[8] = {a0.x, a0.y, a0.z, a0.w, a1.x, a1.y, a1.z, a1.w};
    bh8 ahi, alo;
#pragma unroll
    for (int j = 0; j < 8; ++j) {
      short h = f2bf(av[j]);
      ahi[j] = h;
      alo[j] = f2bf(av[j] - bf2f(h));
    }
#pragma unroll
    for (int i = 0; i < 7; ++i) {
      const size_t boff = (size_t)(i * 16 + cc) * H_ + k + quad * 8;
      bh8 bhi = *(const bh8*)(emb_hi + boff);
      bh8 blo = *(const bh8*)(emb_lo + boff);
      acc[i] = __builtin_amdgcn_mfma_f32_16x16x32_bf16(ahi, bhi, acc[i], 0, 0, 0);
      acc[i] = __builtin_amdgcn_mfma_f32_16x16x32_bf16(alo, bhi, acc[i], 0, 0, 0);
      acc[i] = __builtin_amdgcn_mfma_f32_16x16x32_bf16(ahi, blo, acc[i], 0, 0, 0);
    }
  }

  // store scores: row = m0 + quad*4 + r (C/D row), col t = 16i + cc (C/D col)
#pragma unroll
  for (int i = 0; i < 7; ++i)
#pragma unroll
    for (int r = 0; r < 4; ++r)
      scores[(size_t)(m0 + quad * 4 + r) * TP_ + i * 16 + cc] = acc[i][r];

  // partial softmax stats over the block's 64 l-rows, per t column
  float pm[7], ps[7];
#pragma unroll
  for (int i = 0; i < 7; ++i) {
    float m = fmaxf(fmaxf(acc[i][0], acc[i][1]), fmaxf(acc[i][2], acc[i][3]));
    float s = 0.f;
#pragma unroll
    for (int r = 0; r < 4; ++r) s += __expf(acc[i][r] - m);
    pm[i] = m; ps[i] = s;
  }
#pragma unroll
  for (int d = 16; d < 64; d <<= 1) {   // reduce across quads (same t column)
#pragma unroll
    for (int i = 0; i < 7; ++i) {
      float om = __shfl_xor(pm[i], d, 64);
      float os = __shfl_xor(ps[i], d, 64);
      float M = fmaxf(pm[i], om);
      ps[i] = ps[i] * __expf(pm[i] - M) + os * __expf(om - M);
      pm[i] = M;
    }
  }
  if (lane < 16) {
#pragma unroll
    for (int i = 0; i < 7; ++i) {
      red_m[wave * TP_ + i * 16 + lane] = pm[i];
      red_s[wave * TP_ + i * 16 + lane] = ps[i];
    }
  }
  __syncthreads();
  if (tid < TP_) {
    float M = red_m[tid], S = red_s[tid];
#pragma unroll
    for (int w = 1; w < 4; ++w) {
      float om = red_m[w * TP_ + tid], os = red_s[w * TP_ + tid];
      float nM = fmaxf(M, om);
      S = S * __expf(M - nM) + os * __expf(om - nM);
      M = nM;
    }
    const int b = blockIdx.x >> 4, lblk = blockIdx.x & 15;
    float* p = part + ((size_t)(b * 16 + lblk) * TP_ + tid) * 2;
    p[0] = M; p[1] = S;
  }
}

// ---------------------------------------------------------------------------
// K2: merge partial stats -> softmax -> write attn bf16 [B, 112, L]
// Grid 512 (= B x 8 l-chunks of 128), block 256. LDS transpose for coalesced
// reads ([l][t] layout) AND coalesced writes ([t][l] layout).
// ---------------------------------------------------------------------------
__global__ __launch_bounds__(256) void k2_softmax(
    const float* __restrict__ scores, const float* __restrict__ part,
    short* __restrict__ attn) {
  __shared__ float sM[TP_], sInv[TP_];
  __shared__ short tile[TP_ * 72];
  const int b = blockIdx.x >> 3, chunk = blockIdx.x & 7;
  const int tid = threadIdx.x;
  if (tid < TP_) {
    float M = -1e30f, S = 0.f;
    for (int k = 0; k < 16; ++k) {
      const float* p = part + ((size_t)(b * 16 + k) * TP_ + tid) * 2;
      float om = p[0], os = p[1];
      float nM = fmaxf(M, om);
      S = S * __expf(M - nM) + os * __expf(om - nM);
      M = nM;
    }
    sM[tid] = M;
    sInv[tid] = 1.f / S;
  }
  __syncthreads();
  for (int half = 0; half < 2; ++half) {
    const int l0 = chunk * 128 + half * 64;
    if (half) __syncthreads();            // protect tile re-use
    for (int k = 0; k < 28; ++k) {        // 64 l x 112 t = 7168 elements
      int flat = tid + k * 256;
      int l = flat / TP_, t = flat % TP_;
      float s = scores[((size_t)b * L_ + l0 + l) * TP_ + t];
      float a = __expf(s - sM[t]) * sInv[t];
      tile[t * 72 + l] = f2bf(a);
    }
    __syncthreads();
    for (int k = 0; k < 28; ++k) {
      int flat = tid + k * 256;
      int t = flat >> 6, l = flat & 63;
      attn[((size_t)(b * TP_ + t) << 10) + l0 + l] = tile[t * 72 + l];
    }
  }
}

// ---------------------------------------------------------------------------
// K3: context[b, t, h] = sum_l attn[b,t,l] * origin[b,l,h]   (bf16 ctx out)
// Grid 512 (= B x 8 h-blocks of 64), block 256. A = attn (k-contig, global);
// B = origin fp32, converted to bf16 and staged through transposed LDS tile
// [64 h][32 l] (stride 40).
// ---------------------------------------------------------------------------
__global__ __launch_bounds__(256) void k3_context(
    const short* __restrict__ attn, const float* __restrict__ origin,
    short* __restrict__ ctx) {
  __shared__ short ldsB[64 * 40];
  const int b = blockIdx.x >> 3, hb = (blockIdx.x & 7) * 64;
  const int tid = threadIdx.x;
  const int wave = tid >> 6, lane = tid & 63;
  const int quad = lane >> 4, cc = lane & 15;
  const int loadL = tid >> 3;            // 0..31
  const int loadC = (tid & 7) * 8;       // h chunk base

  f32x4 acc[7];
#pragma unroll
  for (int i = 0; i < 7; ++i) acc[i] = (f32x4){0.f, 0.f, 0.f, 0.f};

  const short* aB   = attn + ((size_t)b * TP_ + cc) * L_ + quad * 8;
  const float* gsrc = origin + ((size_t)b * L_ + loadL) * H_ + hb + loadC;

  for (int l0 = 0; l0 < L_; l0 += 32) {
    float4 v0 = *(const float4*)(gsrc + (size_t)l0 * H_);
    float4 v1 = *(const float4*)(gsrc + (size_t)l0 * H_ + 4);
    float av[8] = {v0.x, v0.y, v0.z, v0.w, v1.x, v1.y, v1.z, v1.w};
    __syncthreads();                      // prior iter's LDS reads done
#pragma unroll
    for (int j = 0; j < 8; ++j) ldsB[(loadC + j) * 40 + loadL] = f2bf(av[j]);
    __syncthreads();
    bh8 bf = *(const bh8*)&ldsB[(wave * 16 + cc) * 40 + quad * 8];
#pragma unroll
    for (int i = 0; i < 7; ++i) {
      bh8 af = *(const bh8*)(aB + (size_t)(i * 16) * L_ + l0);
      acc[i] = __builtin_amdgcn_mfma_f32_16x16x32_bf16(af, bf, acc[i], 0, 0, 0);
    }
  }
  const int hcol = hb + wave * 16 + cc;
#pragma unroll
  for (int i = 0; i < 7; ++i)
#pragma unroll
    for (int r = 0; r < 4; ++r)
      ctx[((size_t)b * TP_ + i * 16 + quad * 4 + r) * H_ + hcol] = f2bf(acc[i][r]);
}

// ---------------------------------------------------------------------------
// K4: out[b,t,c] = sum_h ctx[b,t,h] * W[c,h] + bias[c]   (fp32 out, masked)
// Grid 448 (= B x 7 t-tiles), block 256. Wave w covers c-tiles {w, w+4}.
// ---------------------------------------------------------------------------
__global__ __launch_bounds__(256) void k4_out(
    const short* __restrict__ ctx, const short* __restrict__ W_hi,
    const float* __restrict__ bias, float* __restrict__ out) {
  const int b = blockIdx.x / 7, mt = blockIdx.x % 7;
  const int tid = threadIdx.x;
  const int wave = tid >> 6, lane = tid & 63;
  const int quad = lane >> 4, cc = lane & 15;
  f32x4 acc0 = (f32x4){0.f, 0.f, 0.f, 0.f};
  f32x4 acc1 = (f32x4){0.f, 0.f, 0.f, 0.f};
  const int c0 = wave * 16 + cc;
  const int c1 = (wave + 4) * 16 + cc;
  const bool hasB = (wave < 3);
  const int c0c = (c0 > C_ - 1) ? (C_ - 1) : c0;
  const int c1c = (c1 > C_ - 1) ? (C_ - 1) : c1;
  const short* aptr  = ctx + ((size_t)b * TP_ + mt * 16 + cc) * H_ + quad * 8;
  const short* b0ptr = W_hi + (size_t)c0c * H_ + quad * 8;
  const short* b1ptr = W_hi + (size_t)c1c * H_ + quad * 8;
  for (int k = 0; k < H_; k += 32) {
    bh8 af = *(const bh8*)(aptr + k);
    bh8 bf0 = *(const bh8*)(b0ptr + k);
    acc0 = __builtin_amdgcn_mfma_f32_16x16x32_bf16(af, bf0, acc0, 0, 0, 0);
    if (hasB) {
      bh8 bf1 = *(const bh8*)(b1ptr + k);
      acc1 = __builtin_amdgcn_mfma_f32_16x16x32_bf16(af, bf1, acc1, 0, 0, 0);
    }
  }
  float bias0 = (c0 < C_) ? bias[c0] : 0.f;
  float bias1 = (hasB && c1 < C_) ? bias[c1] : 0.f;
#pragma unroll
  for (int r = 0; r < 4; ++r) {
    int t = mt * 16 + quad * 4 + r;
    if (t < T_) {
      if (c0 < C_) out[((size_t)b * T_ + t) * C_ + c0] = acc0[r] + bias0;
      if (hasB && c1 < C_) out[((size_t)b * T_ + t) * C_ + c1] = acc1[r] + bias1;
    }
  }
}

// ---------------------------------------------------------------------------
extern "C" void kernel_launch(void* const* d_in, const int* in_sizes, int n_in,
                              void* d_out, int out_size, void* d_ws, size_t ws_size,
                              hipStream_t stream) {
  const float* fmap   = (const float*)d_in[0];  // position_fmap [B,L,H] fp32
  const float* origin = (const float*)d_in[1];  // origin_fmap   [B,L,H] fp32
  const float* emb    = (const float*)d_in[2];  // pos_emb       [T,H]   fp32
  const float* W      = (const float*)d_in[3];  // W_gen         [C,H]   fp32
  const float* bias   = (const float*)d_in[4];  // b_gen         [C]     fp32
  float* out = (float*)d_out;                   // [B,T,C] fp32

  char* ws = (char*)d_ws;
  // emb_hi  bf16 [112][512] :   114,688 B @ 0
  // emb_lo  bf16 [112][512] :   114,688 B @ 114,688
  // W_hi    bf16 [ 97][512] :   114,688 B @ 229,376 (alloc padded)
  // scores  fp32 [65536][112]: 29,360,128 B @ 344,064
  // part    fp32 [64][16][112][2]: 917,504 B @ 29,704,192
  // attn    bf16 [64][112][1024]: 14,680,064 B @ 30,621,696
  // ctx     bf16 [64][112][512]:  7,340,032 B @ 45,301,760  (end ~52.6 MB)
  short* emb_hi = (short*)(ws);
  short* emb_lo = (short*)(ws + 114688);
  short* W_hi   = (short*)(ws + 229376);
  float* scores = (float*)(ws + 344064);
  float* part   = (float*)(ws + 29704192);
  short* attn   = (short*)(ws + 30621696);
  short* ctx    = (short*)(ws + 45301760);

  hipLaunchKernelGGL(k0_prep,    dim3(TP_ + C_), dim3(256), 0, stream, emb, W, emb_hi, emb_lo, W_hi);
  hipLaunchKernelGGL(k1_scores,  dim3(1024), dim3(256), 0, stream, fmap, emb_hi, emb_lo, scores, part);
  hipLaunchKernelGGL(k2_softmax, dim3(512),  dim3(256), 0, stream, scores, part, attn);
  hipLaunchKernelGGL(k3_context, dim3(512),  dim3(256), 0, stream, attn, origin, ctx);
  hipLaunchKernelGGL(k4_out,     dim3(448),  dim3(256), 0, stream, ctx, W_hi, bias, out);
}

// Round 3
// 364.361 us; speedup vs baseline: 1.1667x; 1.1667x over previous
//
#include <hip/hip_runtime.h>
#include <hip/hip_bf16.h>

// Problem constants
#define B_   64
#define L_   1024
#define H_   512
#define T_   100
#define C_   97
#define TP_  112   // T padded to 7*16

typedef _Float16 h8 __attribute__((ext_vector_type(8)));   // 8 fp16 (4 VGPRs)
typedef __attribute__((ext_vector_type(4))) float f32x4;   // MFMA C/D

// ---------------------------------------------------------------------------
// k0: prep. pos_emb fp32 -> fp16 [112][512] (rows 100..111 zero);
//     W_gen fp32 -> fp16 [112][512] (rows 97..111 zero). Grid 224.
// ---------------------------------------------------------------------------
__global__ __launch_bounds__(256) void k0_prep(
    const float* __restrict__ emb, const float* __restrict__ W,
    _Float16* __restrict__ embh, _Float16* __restrict__ Wh) {
  const int row = blockIdx.x, tid = threadIdx.x;
  if (row < TP_) {
    for (int j = tid; j < H_; j += 256)
      embh[(size_t)row * H_ + j] =
          (row < T_) ? (_Float16)emb[(size_t)row * H_ + j] : (_Float16)0.f;
  } else {
    const int c = row - TP_;
    for (int j = tid; j < H_; j += 256)
      Wh[(size_t)c * H_ + j] =
          (c < C_) ? (_Float16)W[(size_t)c * H_ + j] : (_Float16)0.f;
  }
}

// ---------------------------------------------------------------------------
// K1: scores = fmap @ emb^T, f16 MFMA (inputs N(0,1): fp16 rel err 2^-11).
// Grid 512 (= B*L/128), block 256: wave handles 32 rows (2 m-tiles) x 112 t.
// Stores sc[row][t] = fp16(s - M_blk) and per-128-row-block stats (M, S).
// ---------------------------------------------------------------------------
__global__ __launch_bounds__(256) void k1_scores(
    const float* __restrict__ fmap, const _Float16* __restrict__ embh,
    _Float16* __restrict__ sc, float* __restrict__ part) {
  __shared__ float red_m[4 * TP_];
  __shared__ float red_s[4 * TP_];
  __shared__ float sMb[TP_];
  const int tid = threadIdx.x;
  const int wave = tid >> 6, lane = tid & 63;
  const int quad = lane >> 4, cc = lane & 15;
  const int m0 = blockIdx.x * 128 + wave * 32;

  f32x4 acc0[7], acc1[7];
#pragma unroll
  for (int i = 0; i < 7; ++i) {
    acc0[i] = (f32x4){0.f, 0.f, 0.f, 0.f};
    acc1[i] = (f32x4){0.f, 0.f, 0.f, 0.f};
  }

  const float* a0p = fmap + (size_t)(m0 + cc) * H_ + quad * 8;
  const float* a1p = a0p + (size_t)16 * H_;
#pragma unroll 2
  for (int k = 0; k < H_; k += 32) {
    float4 x0 = *(const float4*)(a0p + k);
    float4 x1 = *(const float4*)(a0p + k + 4);
    float4 y0 = *(const float4*)(a1p + k);
    float4 y1 = *(const float4*)(a1p + k + 4);
    h8 a0, a1;
    a0[0] = (_Float16)x0.x; a0[1] = (_Float16)x0.y;
    a0[2] = (_Float16)x0.z; a0[3] = (_Float16)x0.w;
    a0[4] = (_Float16)x1.x; a0[5] = (_Float16)x1.y;
    a0[6] = (_Float16)x1.z; a0[7] = (_Float16)x1.w;
    a1[0] = (_Float16)y0.x; a1[1] = (_Float16)y0.y;
    a1[2] = (_Float16)y0.z; a1[3] = (_Float16)y0.w;
    a1[4] = (_Float16)y1.x; a1[5] = (_Float16)y1.y;
    a1[6] = (_Float16)y1.z; a1[7] = (_Float16)y1.w;
#pragma unroll
    for (int i = 0; i < 7; ++i) {
      h8 bf = *(const h8*)(embh + (size_t)(i * 16 + cc) * H_ + k + quad * 8);
      acc0[i] = __builtin_amdgcn_mfma_f32_16x16x32_f16(a0, bf, acc0[i], 0, 0, 0);
      acc1[i] = __builtin_amdgcn_mfma_f32_16x16x32_f16(a1, bf, acc1[i], 0, 0, 0);
    }
  }

  // per-t partial softmax stats over this wave's 32 rows
  float pm[7], ps[7];
#pragma unroll
  for (int i = 0; i < 7; ++i) {
    float m = acc0[i][0];
#pragma unroll
    for (int r = 1; r < 4; ++r) m = fmaxf(m, acc0[i][r]);
#pragma unroll
    for (int r = 0; r < 4; ++r) m = fmaxf(m, acc1[i][r]);
    float s = 0.f;
#pragma unroll
    for (int r = 0; r < 4; ++r) s += __expf(acc0[i][r] - m) + __expf(acc1[i][r] - m);
    pm[i] = m; ps[i] = s;
  }
#pragma unroll
  for (int d = 16; d < 64; d <<= 1) {
#pragma unroll
    for (int i = 0; i < 7; ++i) {
      float om = __shfl_xor(pm[i], d, 64);
      float os = __shfl_xor(ps[i], d, 64);
      float M = fmaxf(pm[i], om);
      ps[i] = ps[i] * __expf(pm[i] - M) + os * __expf(om - M);
      pm[i] = M;
    }
  }
  if (lane < 16) {
#pragma unroll
    for (int i = 0; i < 7; ++i) {
      red_m[wave * TP_ + i * 16 + lane] = pm[i];
      red_s[wave * TP_ + i * 16 + lane] = ps[i];
    }
  }
  __syncthreads();
  if (tid < TP_) {
    float M = red_m[tid], S = red_s[tid];
#pragma unroll
    for (int w = 1; w < 4; ++w) {
      float om = red_m[w * TP_ + tid], os = red_s[w * TP_ + tid];
      float nM = fmaxf(M, om);
      S = S * __expf(M - nM) + os * __expf(om - nM);
      M = nM;
    }
    float* p = part + ((size_t)blockIdx.x * TP_ + tid) * 2;
    p[0] = M; p[1] = S;
    sMb[tid] = M;
  }
  __syncthreads();
#pragma unroll
  for (int i = 0; i < 7; ++i) {
    float mb = sMb[i * 16 + cc];
#pragma unroll
    for (int r = 0; r < 4; ++r) {
      const int row0 = m0 + quad * 4 + r;
      sc[(size_t)row0 * TP_ + i * 16 + cc]        = (_Float16)(acc0[i][r] - mb);
      sc[(size_t)(row0 + 16) * TP_ + i * 16 + cc] = (_Float16)(acc1[i][r] - mb);
    }
  }
}

// ---------------------------------------------------------------------------
// K2: merge 8 per-slab stats -> pure streaming softmax.
// attn[b][l][t] = exp(sc + (M_blk - M)) / S, fp16, same layout as sc.
// Grid 512 (= B x 8 slabs of 128 rows), block 256. No transpose, no conflicts.
// ---------------------------------------------------------------------------
__global__ __launch_bounds__(256) void k2_softmax(
    const _Float16* __restrict__ sc, const float* __restrict__ part,
    _Float16* __restrict__ attn) {
  __shared__ float sAdj[TP_], sInv[TP_];
  const int b = blockIdx.x >> 3, lblk = blockIdx.x & 7;
  const int tid = threadIdx.x;
  if (tid < TP_) {
    float M = -1e30f, S = 0.f;
    for (int k = 0; k < 8; ++k) {
      const float* p = part + ((size_t)(b * 8 + k) * TP_ + tid) * 2;
      float om = p[0], os = p[1];
      float nM = fmaxf(M, om);
      S = S * __expf(M - nM) + os * __expf(om - nM);
      M = nM;
    }
    sInv[tid] = 1.f / S;
    sAdj[tid] = part[((size_t)(b * 8 + lblk) * TP_ + tid) * 2] - M;
  }
  __syncthreads();
  const _Float16* sp = sc + (size_t)blockIdx.x * (128 * TP_);
  _Float16* ap = attn + (size_t)blockIdx.x * (128 * TP_);
  for (int f = tid * 8; f < 128 * TP_; f += 2048) {
    h8 v = *(const h8*)(sp + f);
    const int t0 = f % TP_;   // 8 elements stay within one row (112 % 8 == 0)
    h8 o;
#pragma unroll
    for (int j = 0; j < 8; ++j)
      o[j] = (_Float16)(__expf((float)v[j] + sAdj[t0 + j]) * sInv[t0 + j]);
    *(h8*)(ap + f) = o;
  }
}

// ---------------------------------------------------------------------------
// K3: ctxT[b][h][t] = sum_l origin[b][l][h] * attn[b][l][t]   (fp32 out)
// Transposeless: A = origin^T (m=h, k=l via 64B-coalesced scalar loads),
// B = attn (imm-offset u16 loads, L2-resident). No LDS, no barriers.
// Grid 512 (= B x 8 h-blocks of 64), block 256 (wave = one 16-h m-tile).
// ---------------------------------------------------------------------------
__global__ __launch_bounds__(256) void k3_context(
    const _Float16* __restrict__ attn, const float* __restrict__ origin,
    float* __restrict__ ctxT) {
  const int b = blockIdx.x >> 3, hb = (blockIdx.x & 7) * 64;
  const int tid = threadIdx.x;
  const int wave = tid >> 6, lane = tid & 63;
  const int quad = lane >> 4, cc = lane & 15;
  const int hA = hb + wave * 16 + cc;          // A-operand m index

  f32x4 acc[7];
#pragma unroll
  for (int i = 0; i < 7; ++i) acc[i] = (f32x4){0.f, 0.f, 0.f, 0.f};

  const float* op = origin + (size_t)b * L_ * H_ + (size_t)(quad * 8) * H_ + hA;
  const _Float16* bp = attn + (size_t)b * L_ * TP_ + (size_t)(quad * 8) * TP_;

#pragma unroll 2
  for (int l0 = 0; l0 < L_; l0 += 32) {
    h8 a;
#pragma unroll
    for (int j = 0; j < 8; ++j) a[j] = (_Float16)op[(size_t)(l0 + j) * H_];
#pragma unroll
    for (int i = 0; i < 7; ++i) {
      h8 bf;
#pragma unroll
      for (int j = 0; j < 8; ++j) bf[j] = bp[(size_t)(l0 + j) * TP_ + i * 16 + cc];
      acc[i] = __builtin_amdgcn_mfma_f32_16x16x32_f16(a, bf, acc[i], 0, 0, 0);
    }
  }
  const int hrow = hb + wave * 16 + quad * 4;  // D row base
#pragma unroll
  for (int i = 0; i < 7; ++i)
#pragma unroll
    for (int r = 0; r < 4; ++r)
      ctxT[((size_t)b * H_ + hrow + r) * TP_ + i * 16 + cc] = acc[i][r];
}

// ---------------------------------------------------------------------------
// K4: out[b,t,c] = sum_h ctxT[b][h][t] * W[c][h] + bias[c]   (fp32 out)
// Grid 448 (= B x 7 t-tiles), block 256. Wave w covers c-tiles {w, w+4}.
// ---------------------------------------------------------------------------
__global__ __launch_bounds__(256) void k4_out(
    const float* __restrict__ ctxT, const _Float16* __restrict__ Wh,
    const float* __restrict__ bias, float* __restrict__ out) {
  const int b = blockIdx.x / 7, mt = blockIdx.x % 7;
  const int tid = threadIdx.x;
  const int wave = tid >> 6, lane = tid & 63;
  const int quad = lane >> 4, cc = lane & 15;
  f32x4 acc0 = (f32x4){0.f, 0.f, 0.f, 0.f};
  f32x4 acc1 = (f32x4){0.f, 0.f, 0.f, 0.f};
  const int c0 = wave * 16 + cc;
  const int c1 = (wave + 4) * 16 + cc;          // < 112 when hasB
  const bool hasB = (wave < 3);
  const float* apc = ctxT + ((size_t)b * H_ + quad * 8) * TP_ + mt * 16 + cc;
  const _Float16* b0p = Wh + (size_t)c0 * H_ + quad * 8;
  const _Float16* b1p = Wh + (size_t)(hasB ? c1 : c0) * H_ + quad * 8;
  for (int k = 0; k < H_; k += 32) {
    h8 a;
#pragma unroll
    for (int j = 0; j < 8; ++j) a[j] = (_Float16)apc[(size_t)(k + j) * TP_];
    h8 bf0 = *(const h8*)(b0p + k);
    acc0 = __builtin_amdgcn_mfma_f32_16x16x32_f16(a, bf0, acc0, 0, 0, 0);
    if (hasB) {
      h8 bf1 = *(const h8*)(b1p + k);
      acc1 = __builtin_amdgcn_mfma_f32_16x16x32_f16(a, bf1, acc1, 0, 0, 0);
    }
  }
  const float bias0 = (c0 < C_) ? bias[c0] : 0.f;
  const float bias1 = (hasB && c1 < C_) ? bias[c1] : 0.f;
#pragma unroll
  for (int r = 0; r < 4; ++r) {
    const int t = mt * 16 + quad * 4 + r;
    if (t < T_) {
      if (c0 < C_) out[((size_t)b * T_ + t) * C_ + c0] = acc0[r] + bias0;
      if (hasB && c1 < C_) out[((size_t)b * T_ + t) * C_ + c1] = acc1[r] + bias1;
    }
  }
}

// ---------------------------------------------------------------------------
extern "C" void kernel_launch(void* const* d_in, const int* in_sizes, int n_in,
                              void* d_out, int out_size, void* d_ws, size_t ws_size,
                              hipStream_t stream) {
  const float* fmap   = (const float*)d_in[0];  // [B,L,H] fp32
  const float* origin = (const float*)d_in[1];  // [B,L,H] fp32
  const float* emb    = (const float*)d_in[2];  // [T,H]   fp32
  const float* W      = (const float*)d_in[3];  // [C,H]   fp32
  const float* bias   = (const float*)d_in[4];  // [C]     fp32
  float* out = (float*)d_out;                   // [B,T,C] fp32

  char* ws = (char*)d_ws;
  // embh f16 [112][512]        :    114,688 B @ 0
  // Wh   f16 [112][512]        :    114,688 B @ 114,688
  // sc   f16 [65536][112]      : 14,680,064 B @ 229,376
  // part f32 [512][112][2]     :    458,752 B @ 14,909,440
  // attn f16 [65536][112]      : 14,680,064 B @ 15,368,192
  // ctxT f32 [64][512][112]    : 14,680,064 B @ 30,048,256   (end 44.7 MB)
  _Float16* embh = (_Float16*)(ws);
  _Float16* Wh   = (_Float16*)(ws + 114688);
  _Float16* sc   = (_Float16*)(ws + 229376);
  float*    part = (float*)   (ws + 14909440);
  _Float16* attn = (_Float16*)(ws + 15368192);
  float*    ctxT = (float*)   (ws + 30048256);

  hipLaunchKernelGGL(k0_prep,    dim3(224), dim3(256), 0, stream, emb, W, embh, Wh);
  hipLaunchKernelGGL(k1_scores,  dim3(512), dim3(256), 0, stream, fmap, embh, sc, part);
  hipLaunchKernelGGL(k2_softmax, dim3(512), dim3(256), 0, stream, sc, part, attn);
  hipLaunchKernelGGL(k3_context, dim3(512), dim3(256), 0, stream, attn, origin, ctxT);
  hipLaunchKernelGGL(k4_out,     dim3(448), dim3(256), 0, stream, ctxT, Wh, bias, out);
}